// Round 3
// baseline (316.575 us; speedup 1.0000x reference)
//
#include <hip/hip_runtime.h>
#include <hip/hip_bf16.h>

typedef __attribute__((ext_vector_type(4))) float f32x4;
typedef __attribute__((ext_vector_type(8))) short s16x8;
typedef __attribute__((ext_vector_type(4))) short s16x4;
typedef unsigned short u16;

// ---- helpers -------------------------------------------------------------

__device__ __forceinline__ f32x4 mfma16(s16x8 a, s16x8 b, f32x4 c) {
    return __builtin_amdgcn_mfma_f32_16x16x32_bf16(a, b, c, 0, 0, 0);
}

// RNE fp32 -> bf16 (bit trick)
__device__ __forceinline__ u16 bf(float f) {
    union { float f; unsigned u; } x; x.f = f;
    return (u16)((x.u + 0x7fffu + ((x.u >> 16) & 1u)) >> 16);
}
__device__ __forceinline__ unsigned pkbf(float a, float b) {
    union { float f; unsigned u; } x, y; x.f = a; y.f = b;
    unsigned ra = x.u + 0x7fffu + ((x.u >> 16) & 1u);
    unsigned rb = y.u + 0x7fffu + ((y.u >> 16) & 1u);
    return (ra >> 16) | (rb & 0xffff0000u);
}

// async global->LDS, 16B per lane (wave-uniform LDS base + lane*16)
__device__ __forceinline__ void gl_lds16(const void* g, void* l) {
    __builtin_amdgcn_global_load_lds(
        (const __attribute__((address_space(1))) unsigned*)g,
        (__attribute__((address_space(3))) unsigned*)l, 16, 0, 0);
}

// ---- K0: merged fp32 -> bf16 convert (x, Wq, Wk, Wv, Wo in one launch) ---

__global__ __launch_bounds__(256) void cvt_all_kernel(
        const float* __restrict__ x,  const float* __restrict__ Wq,
        const float* __restrict__ Wk, const float* __restrict__ Wv,
        const float* __restrict__ Wo,
        u16* __restrict__ xb, u16* __restrict__ wb, u16* __restrict__ wob) {
    int i = blockIdx.x * 256 + threadIdx.x;
    const float* src; u16* dst; int off;
    if (i < 1048576)      { src = x;  dst = xb;            off = i; }
    else if (i < 1310720) { src = Wq; dst = wb;            off = i - 1048576; }
    else if (i < 1572864) { src = Wk; dst = wb + 1048576;  off = i - 1310720; }
    else if (i < 1835008) { src = Wv; dst = wb + 2097152;  off = i - 1572864; }
    else if (i < 1851392) { src = Wo; dst = wob;           off = i - 1835008; }
    else return;
    f32x4 v = ((const f32x4*)src)[off];
    union { s16x4 v; unsigned u[2]; } r;
    r.u[0] = pkbf(v.x, v.y);
    r.u[1] = pkbf(v.z, v.w);
    ((s16x4*)dst)[off] = r.v;
}

// ---- K1: QKV projections, m97-style LDS-staged 128x128 GEMM -------------

__global__ __launch_bounds__(256, 3) void qkv_kernel(
        const u16* __restrict__ xb, const u16* __restrict__ wb,
        const float* __restrict__ bq, const float* __restrict__ bk,
        const float* __restrict__ bv,
        u16* __restrict__ qo, u16* __restrict__ kTo, u16* __restrict__ vTo) {
    __shared__ u16 As[128 * 32];
    __shared__ u16 Bs[128 * 32];
    int bx   = blockIdx.x % 24;
    int by   = blockIdx.x / 24;
    int tid  = threadIdx.x;
    int lane = tid & 63, w = tid >> 6;
    int l15  = lane & 15, quad = lane >> 4;
    int wr   = w >> 1, wc = w & 1;

    const u16* Ag = xb + (size_t)(by * 128 + (tid >> 2)) * 1024 + (tid & 3) * 8;
    const u16* Bg = wb + (size_t)(bx * 128 + (tid >> 2)) * 1024 + (tid & 3) * 8;
    u16* Al = As + tid * 8;
    u16* Bl = Bs + tid * 8;

    const u16* abase = As + (wr * 64 + l15) * 32 + quad * 8;
    const u16* bbase = Bs + (wc * 64 + l15) * 32 + quad * 8;

    f32x4 acc[4][4] = {};
    for (int k0 = 0; k0 < 1024; k0 += 32) {
        gl_lds16(Ag + k0, Al);
        gl_lds16(Ag + 64 * 1024 + k0, Al + 64 * 32);
        gl_lds16(Bg + k0, Bl);
        gl_lds16(Bg + 64 * 1024 + k0, Bl + 64 * 32);
        __syncthreads();
        s16x8 a[4], b[4];
#pragma unroll
        for (int mi = 0; mi < 4; mi++) a[mi] = *(const s16x8*)(abase + mi * 16 * 32);
#pragma unroll
        for (int nj = 0; nj < 4; nj++) b[nj] = *(const s16x8*)(bbase + nj * 16 * 32);
#pragma unroll
        for (int mi = 0; mi < 4; mi++)
#pragma unroll
            for (int nj = 0; nj < 4; nj++) acc[mi][nj] = mfma16(a[mi], b[nj], acc[mi][nj]);
        __syncthreads();
    }

    int fblk = (bx * 128 + wc * 64) >> 6;
    int mat  = fblk >> 4, h = fblk & 15;
    const float* bias = (mat == 0) ? bq : (mat == 1 ? bk : bv);
#pragma unroll
    for (int nj = 0; nj < 4; nj++) {
        int e = nj * 16 + l15;
        float bb = bias[h * 64 + e];
#pragma unroll
        for (int mi = 0; mi < 4; mi++) {
            int n0 = by * 128 + wr * 64 + mi * 16 + quad * 4;
            f32x4 c = acc[mi][nj];
            if (mat == 0) {
                u16* p = qo + ((size_t)h * 4096 + n0) * 64 + e;
#pragma unroll
                for (int r = 0; r < 4; r++) p[(size_t)r * 64] = bf(c[r] + bb);
            } else {
                u16* p = (mat == 1 ? kTo : vTo) + ((size_t)h * 64 + e) * 4096 + n0;
                union { s16x4 v; u16 s[4]; } pk;
#pragma unroll
                for (int r = 0; r < 4; r++) pk.s[r] = bf(c[r] + bb);
                *(s16x4*)p = pk.v;
            }
        }
    }
}

// ---- K2: kp/vp — m13-style streaming: one independent wave per tile -----
// 8192 waves = 2p x 16h x 16jt x 16ks; 2048 blocks; no LDS, no barriers.
// Wave tile: 16 j-rows x 64 e, K=256 in 8 steps of 32.
// Distance-1 rotated prefetch: step it+1's 6 loads (2 A f32x4 + 4 B s16x8)
// are issued before step it's convert+MFMA, so each wave keeps ~96B/lane
// in flight; TLP (16 waves/CU) does the rest. Streaming BW comes from
// wave count, not per-wave pipelining (m13 lesson).

__global__ __launch_bounds__(256) void kpvp_kernel(
        const float* __restrict__ Ew, const float* __restrict__ Fw,
        const u16* __restrict__ kT, const u16* __restrict__ vT,
        float* __restrict__ accs) {
    int tid  = threadIdx.x;
    int w = tid >> 6, lane = tid & 63;
    int l15 = lane & 15, quad = lane >> 4;
    int gw = blockIdx.x * 4 + w;
    int ks = gw & 15, jt = (gw >> 4) & 15, h = (gw >> 8) & 15, p = gw >> 12;

    const float* Ap = (p ? Fw : Ew)
        + (size_t)(h * 256 + jt * 16 + l15) * 4096 + ks * 256 + quad * 8;
    const u16* Bp = (p ? vT : kT)
        + (size_t)(h * 64 + l15) * 4096 + ks * 256 + quad * 8;

    f32x4 acc[4] = {};
    f32x4 ca0 = *(const f32x4*)(Ap);
    f32x4 ca1 = *(const f32x4*)(Ap + 4);
    s16x8 cb0 = *(const s16x8*)(Bp);
    s16x8 cb1 = *(const s16x8*)(Bp + 1 * 16 * 4096);
    s16x8 cb2 = *(const s16x8*)(Bp + 2 * 16 * 4096);
    s16x8 cb3 = *(const s16x8*)(Bp + 3 * 16 * 4096);
#pragma unroll
    for (int it = 0; it < 8; ++it) {
        // prefetch next step (last iter re-reads k=0: in-bounds, L1-hot, unused cost ~0)
        int kn = (it < 7) ? (it + 1) * 32 : 0;
        f32x4 na0 = *(const f32x4*)(Ap + kn);
        f32x4 na1 = *(const f32x4*)(Ap + kn + 4);
        s16x8 nb0 = *(const s16x8*)(Bp + kn);
        s16x8 nb1 = *(const s16x8*)(Bp + 1 * 16 * 4096 + kn);
        s16x8 nb2 = *(const s16x8*)(Bp + 2 * 16 * 4096 + kn);
        s16x8 nb3 = *(const s16x8*)(Bp + 3 * 16 * 4096 + kn);
        union { s16x8 q; unsigned u[4]; } rr;
        rr.u[0] = pkbf(ca0.x, ca0.y);
        rr.u[1] = pkbf(ca0.z, ca0.w);
        rr.u[2] = pkbf(ca1.x, ca1.y);
        rr.u[3] = pkbf(ca1.z, ca1.w);
        acc[0] = mfma16(rr.q, cb0, acc[0]);
        acc[1] = mfma16(rr.q, cb1, acc[1]);
        acc[2] = mfma16(rr.q, cb2, acc[2]);
        acc[3] = mfma16(rr.q, cb3, acc[3]);
        ca0 = na0; ca1 = na1;
        cb0 = nb0; cb1 = nb1; cb2 = nb2; cb3 = nb3;
    }

    size_t base = (size_t)ks * 524288
        + ((size_t)(p * 16 + h) * 256 + jt * 16 + quad * 4) * 64 + l15;
#pragma unroll
    for (int nt = 0; nt < 4; nt++)
#pragma unroll
        for (int r = 0; r < 4; r++)
            accs[base + (size_t)r * 64 + nt * 16] = acc[nt][r];
}

// ---- K3: reduce 16 slices + bias + pack ---------------------------------

__global__ __launch_bounds__(256) void packkv_kernel(
        const float* __restrict__ accs, const float* __restrict__ Eb,
        const float* __restrict__ Fb, u16* __restrict__ kp, u16* __restrict__ vpT) {
    int idx = blockIdx.x * 256 + threadIdx.x;
    float v = 0.f;
#pragma unroll
    for (int s = 0; s < 16; s++) v += accs[idx + (size_t)s * 524288];
    int p = idx >> 18, h = (idx >> 14) & 15, j = (idx >> 6) & 255, e = idx & 63;
    if (p == 0) {
        v += Eb[h * 256 + j];
        kp[((size_t)(h * 256 + j)) * 64 + e] = bf(v * 0.125f);  // fold 1/sqrt(64)
    } else {
        v += Fb[h * 256 + j];
        vpT[((size_t)(h * 64 + e)) * 256 + j] = bf(v);
    }
}

// ---- K4: attention: score -> softmax -> PV ------------------------------

__global__ __launch_bounds__(256) void attn_kernel(
        const u16* __restrict__ q, const u16* __restrict__ kp,
        const u16* __restrict__ vpT, u16* __restrict__ zs) {
    __shared__ u16 ps[4][16][256];
    int bm   = blockIdx.x & 63, h = blockIdx.x >> 6;
    int lane = threadIdx.x & 63, w = threadIdx.x >> 6;
    int l15  = lane & 15, quad = lane >> 4;
    int nbase = bm * 64 + w * 16;

    f32x4 s[16] = {};
    const u16* qp  = q  + ((size_t)h * 4096 + nbase + l15) * 64 + quad * 8;
    const u16* kpp = kp + ((size_t)h * 256 + l15) * 64 + quad * 8;
#pragma unroll
    for (int e0 = 0; e0 < 64; e0 += 32) {
        s16x8 a = *(const s16x8*)(qp + e0);
#pragma unroll
        for (int jt = 0; jt < 16; jt++) {
            s16x8 b = *(const s16x8*)(kpp + jt * 16 * 64 + e0);
            s[jt] = mfma16(a, b, s[jt]);
        }
    }

    float lsum[4];
#pragma unroll
    for (int r = 0; r < 4; r++) {
        float m = s[0][r];
#pragma unroll
        for (int jt = 1; jt < 16; jt++) m = fmaxf(m, s[jt][r]);
        m = fmaxf(m, __shfl_xor(m, 1));
        m = fmaxf(m, __shfl_xor(m, 2));
        m = fmaxf(m, __shfl_xor(m, 4));
        m = fmaxf(m, __shfl_xor(m, 8));
        float l = 0.f;
#pragma unroll
        for (int jt = 0; jt < 16; jt++) {
            float pv = __expf(s[jt][r] - m);
            s[jt][r] = pv;
            l += pv;
        }
        l += __shfl_xor(l, 1);
        l += __shfl_xor(l, 2);
        l += __shfl_xor(l, 4);
        l += __shfl_xor(l, 8);
        lsum[r] = l;
    }

#pragma unroll
    for (int jt = 0; jt < 16; jt++)
#pragma unroll
        for (int r = 0; r < 4; r++)
            ps[w][quad * 4 + r][jt * 16 + l15] = bf(s[jt][r]);
    __syncthreads();

    f32x4 z[4] = {};
    const u16* vp = vpT + ((size_t)h * 64 + l15) * 256 + quad * 8;
#pragma unroll
    for (int kj = 0; kj < 8; kj++) {
        s16x8 a = *(const s16x8*)&ps[w][l15][kj * 32 + quad * 8];
#pragma unroll
        for (int et = 0; et < 4; et++) {
            s16x8 b = *(const s16x8*)(vp + et * 16 * 256 + kj * 32);
            z[et] = mfma16(a, b, z[et]);
        }
    }
#pragma unroll
    for (int et = 0; et < 4; et++) {
        int e = et * 16 + l15;
        u16* o = zs + ((size_t)(nbase + quad * 4)) * 1024 + h * 64 + e;
#pragma unroll
        for (int r = 0; r < 4; r++) o[(size_t)r * 1024] = bf(z[et][r] / lsum[r]);
    }
}

// ---- K5: out = zs @ Wo^T, split-K=4, disjoint slices (no atomics) -------

__global__ __launch_bounds__(256) void out_kernel(
        const u16* __restrict__ zs, const u16* __restrict__ wob,
        float* __restrict__ oslice) {
    int ks   = blockIdx.x & 3;
    int bm   = blockIdx.x >> 2;
    int lane = threadIdx.x & 63, w = threadIdx.x >> 6;
    int l15  = lane & 15, quad = lane >> 4;
    int row0 = bm * 128 + w * 32;

    const u16* A = zs  + (size_t)(row0 + l15) * 1024 + ks * 256 + quad * 8;
    const u16* B = wob + (size_t)l15 * 1024 + ks * 256 + quad * 8;

    f32x4 acc[2][4] = {};
    for (int k = 0; k < 256; k += 32) {
        s16x8 a0 = *(const s16x8*)(A + k);
        s16x8 a1 = *(const s16x8*)(A + 16 * 1024 + k);
#pragma unroll
        for (int nt = 0; nt < 4; nt++) {
            s16x8 bv = *(const s16x8*)(B + (size_t)nt * 16 * 1024 + k);
            acc[0][nt] = mfma16(a0, bv, acc[0][nt]);
            acc[1][nt] = mfma16(a1, bv, acc[1][nt]);
        }
    }
    float* os = oslice + (size_t)ks * 262144;
#pragma unroll
    for (int mt = 0; mt < 2; mt++)
#pragma unroll
        for (int nt = 0; nt < 4; nt++) {
            int e = nt * 16 + l15;
            int n0 = row0 + mt * 16 + quad * 4;
            float* o = os + (size_t)n0 * 64 + e;
#pragma unroll
            for (int r = 0; r < 4; r++) o[(size_t)r * 64] = acc[mt][nt][r];
        }
}

__global__ __launch_bounds__(256) void outred_kernel(
        const float* __restrict__ oslice, float* __restrict__ out) {
    int i = blockIdx.x * 256 + threadIdx.x;   // 262144 total
    out[i] = oslice[i] + oslice[i + 262144] + oslice[i + 524288] + oslice[i + 786432];
}

// ---- launch --------------------------------------------------------------

extern "C" void kernel_launch(void* const* d_in, const int* in_sizes, int n_in,
                              void* d_out, int out_size, void* d_ws, size_t ws_size,
                              hipStream_t stream) {
    const float* x  = (const float*)d_in[0];
    const float* Wq = (const float*)d_in[1];
    const float* bq = (const float*)d_in[2];
    const float* Wk = (const float*)d_in[3];
    const float* bk = (const float*)d_in[4];
    const float* Wv = (const float*)d_in[5];
    const float* bv = (const float*)d_in[6];
    const float* Ew = (const float*)d_in[7];
    const float* Eb = (const float*)d_in[8];
    const float* Fw = (const float*)d_in[9];
    const float* Fb = (const float*)d_in[10];
    const float* Wo = (const float*)d_in[11];

    char* ws = (char*)d_ws;
    u16*   qb   = (u16*)(ws + 0);          // H*N*E bf16            8 MB
    u16*   kT   = (u16*)(ws + 8388608);    // H*E*N bf16            8 MB
    u16*   vT   = (u16*)(ws + 16777216);   // H*E*N bf16            8 MB
    u16*   zsb  = (u16*)(ws + 25165824);   // N*(H*E) bf16          8 MB
    float* accs = (float*)(ws + 33554432); // 16 slices x 2 MB fp32 32 MB (reused as oslice)
    u16*   kp   = (u16*)(ws + 67108864);   // H*256*64 bf16       0.5 MB
    u16*   vpT  = (u16*)(ws + 67633152);   // H*64*256 bf16       0.5 MB
    u16*   xb   = (u16*)(ws + 68157440);   // N*D bf16              8 MB
    u16*   wb   = (u16*)(ws + 76546048);   // 3*H*E*D bf16          6 MB
    u16*   wob  = (u16*)(ws + 82837504);   // E*(H*E) bf16       128 KB

    cvt_all_kernel<<<7232, 256, 0, stream>>>(x, Wq, Wk, Wv, Wo, xb, wb, wob);
    qkv_kernel<<<768, 256, 0, stream>>>(xb, wb, bq, bk, bv, qb, kT, vT);
    kpvp_kernel<<<2048, 256, 0, stream>>>(Ew, Fw, kT, vT, accs);
    packkv_kernel<<<2048, 256, 0, stream>>>(accs, Eb, Fb, kp, vpT);
    attn_kernel<<<1024, 256, 0, stream>>>(qb, kp, vpT, zsb);
    out_kernel<<<128, 256, 0, stream>>>(zsb, wob, (float*)accs);   // accs free -> oslice
    outred_kernel<<<1024, 256, 0, stream>>>((const float*)accs, (float*)d_out);
}

// Round 5
// 293.317 us; speedup vs baseline: 1.0793x; 1.0793x over previous
//
#include <hip/hip_runtime.h>
#include <hip/hip_bf16.h>

typedef __attribute__((ext_vector_type(4))) float f32x4;
typedef __attribute__((ext_vector_type(8))) short s16x8;
typedef __attribute__((ext_vector_type(4))) short s16x4;
typedef unsigned short u16;

// ---- helpers -------------------------------------------------------------

__device__ __forceinline__ f32x4 mfma16(s16x8 a, s16x8 b, f32x4 c) {
    return __builtin_amdgcn_mfma_f32_16x16x32_bf16(a, b, c, 0, 0, 0);
}

// RNE fp32 -> bf16 (bit trick)
__device__ __forceinline__ u16 bf(float f) {
    union { float f; unsigned u; } x; x.f = f;
    return (u16)((x.u + 0x7fffu + ((x.u >> 16) & 1u)) >> 16);
}
__device__ __forceinline__ unsigned pkbf(float a, float b) {
    union { float f; unsigned u; } x, y; x.f = a; y.f = b;
    unsigned ra = x.u + 0x7fffu + ((x.u >> 16) & 1u);
    unsigned rb = y.u + 0x7fffu + ((y.u >> 16) & 1u);
    return (ra >> 16) | (rb & 0xffff0000u);
}

// async global->LDS, 16B per lane (wave-uniform LDS base + lane*16)
__device__ __forceinline__ void gl_lds16(const void* g, void* l) {
    __builtin_amdgcn_global_load_lds(
        (const __attribute__((address_space(1))) unsigned*)g,
        (__attribute__((address_space(3))) unsigned*)l, 16, 0, 0);
}

// ---- K0: merged fp32 -> bf16 convert (x, Wq, Wk, Wv, Wo in one launch) ---

__global__ __launch_bounds__(256) void cvt_all_kernel(
        const float* __restrict__ x,  const float* __restrict__ Wq,
        const float* __restrict__ Wk, const float* __restrict__ Wv,
        const float* __restrict__ Wo,
        u16* __restrict__ xb, u16* __restrict__ wb, u16* __restrict__ wob) {
    int i = blockIdx.x * 256 + threadIdx.x;
    const float* src; u16* dst; int off;
    if (i < 1048576)      { src = x;  dst = xb;            off = i; }
    else if (i < 1310720) { src = Wq; dst = wb;            off = i - 1048576; }
    else if (i < 1572864) { src = Wk; dst = wb + 1048576;  off = i - 1310720; }
    else if (i < 1835008) { src = Wv; dst = wb + 2097152;  off = i - 1572864; }
    else if (i < 1851392) { src = Wo; dst = wob;           off = i - 1835008; }
    else return;
    f32x4 v = ((const f32x4*)src)[off];
    union { s16x4 v; unsigned u[2]; } r;
    r.u[0] = pkbf(v.x, v.y);
    r.u[1] = pkbf(v.z, v.w);
    ((s16x4*)dst)[off] = r.v;
}

// ---- K1: QKV projections, m97-style LDS-staged 128x128 GEMM -------------

__global__ __launch_bounds__(256, 3) void qkv_kernel(
        const u16* __restrict__ xb, const u16* __restrict__ wb,
        const float* __restrict__ bq, const float* __restrict__ bk,
        const float* __restrict__ bv,
        u16* __restrict__ qo, u16* __restrict__ kTo, u16* __restrict__ vTo) {
    __shared__ u16 As[128 * 32];
    __shared__ u16 Bs[128 * 32];
    int bx   = blockIdx.x % 24;
    int by   = blockIdx.x / 24;
    int tid  = threadIdx.x;
    int lane = tid & 63, w = tid >> 6;
    int l15  = lane & 15, quad = lane >> 4;
    int wr   = w >> 1, wc = w & 1;

    const u16* Ag = xb + (size_t)(by * 128 + (tid >> 2)) * 1024 + (tid & 3) * 8;
    const u16* Bg = wb + (size_t)(bx * 128 + (tid >> 2)) * 1024 + (tid & 3) * 8;
    u16* Al = As + tid * 8;
    u16* Bl = Bs + tid * 8;

    const u16* abase = As + (wr * 64 + l15) * 32 + quad * 8;
    const u16* bbase = Bs + (wc * 64 + l15) * 32 + quad * 8;

    f32x4 acc[4][4] = {};
    for (int k0 = 0; k0 < 1024; k0 += 32) {
        gl_lds16(Ag + k0, Al);
        gl_lds16(Ag + 64 * 1024 + k0, Al + 64 * 32);
        gl_lds16(Bg + k0, Bl);
        gl_lds16(Bg + 64 * 1024 + k0, Bl + 64 * 32);
        __syncthreads();
        s16x8 a[4], b[4];
#pragma unroll
        for (int mi = 0; mi < 4; mi++) a[mi] = *(const s16x8*)(abase + mi * 16 * 32);
#pragma unroll
        for (int nj = 0; nj < 4; nj++) b[nj] = *(const s16x8*)(bbase + nj * 16 * 32);
#pragma unroll
        for (int mi = 0; mi < 4; mi++)
#pragma unroll
            for (int nj = 0; nj < 4; nj++) acc[mi][nj] = mfma16(a[mi], b[nj], acc[mi][nj]);
        __syncthreads();
    }

    int fblk = (bx * 128 + wc * 64) >> 6;
    int mat  = fblk >> 4, h = fblk & 15;
    const float* bias = (mat == 0) ? bq : (mat == 1 ? bk : bv);
#pragma unroll
    for (int nj = 0; nj < 4; nj++) {
        int e = nj * 16 + l15;
        float bb = bias[h * 64 + e];
#pragma unroll
        for (int mi = 0; mi < 4; mi++) {
            int n0 = by * 128 + wr * 64 + mi * 16 + quad * 4;
            f32x4 c = acc[mi][nj];
            if (mat == 0) {
                u16* p = qo + ((size_t)h * 4096 + n0) * 64 + e;
#pragma unroll
                for (int r = 0; r < 4; r++) p[(size_t)r * 64] = bf(c[r] + bb);
            } else {
                u16* p = (mat == 1 ? kTo : vTo) + ((size_t)h * 64 + e) * 4096 + n0;
                union { s16x4 v; u16 s[4]; } pk;
#pragma unroll
                for (int r = 0; r < 4; r++) pk.s[r] = bf(c[r] + bb);
                *(s16x4*)p = pk.v;
            }
        }
    }
}

// ---- K2: kp/vp — min-traffic: split-K=2 blocks, wave-split-K in-block ---
// grid: b = (((p*16+h)<<2 | jb)<<1) | ks  (256 blocks, 512 thr, 8 waves).
// Block: 64 j x 64 e, K-chunk 2048. Waves: wj = w>>2 (j-half, 32 rows),
// wk = w&3 (K-quarter, 512). Waves PARTITION K, so the block reads each
// A/B byte exactly once (no per-wave B duplication -> round-3's mistake).
// Cross-wave K-reduce via padded LDS; only 2 fp32 slices go to HBM
// (accs 8 MB round-trip vs 64 MB at split-16). Inner loop = round-1's
// proven register-direct pattern (unroll-2, 8 loads/step in flight).

__global__ __launch_bounds__(512) void kpvp_kernel(
        const float* __restrict__ Ew, const float* __restrict__ Fw,
        const u16* __restrict__ kT, const u16* __restrict__ vT,
        float* __restrict__ accs) {
    __shared__ float Ls[8][32][68];   // 69.6 KB, +4 pad kills quad-row conflicts
    int b    = blockIdx.x;
    int ks   = b & 1, jb = (b >> 1) & 3, h = (b >> 3) & 15, p = b >> 7;
    int tid  = threadIdx.x;
    int w    = tid >> 6, lane = tid & 63;
    int wj   = w >> 2, wk = w & 3;
    int l15  = lane & 15, quad = lane >> 4;

    const float* Ap = (p ? Fw : Ew)
        + (size_t)(h * 256 + jb * 64 + wj * 32 + l15) * 4096
        + ks * 2048 + wk * 512 + quad * 8;
    const u16* Bp = (p ? vT : kT)
        + (size_t)(h * 64 + l15) * 4096 + ks * 2048 + wk * 512 + quad * 8;

    f32x4 acc[2][4] = {};
#pragma unroll 2
    for (int kk = 0; kk < 512; kk += 32) {
        s16x8 a[2], bb[4];
#pragma unroll
        for (int mt = 0; mt < 2; mt++) {
            f32x4 v0 = *(const f32x4*)(Ap + (size_t)mt * 16 * 4096 + kk);
            f32x4 v1 = *(const f32x4*)(Ap + (size_t)mt * 16 * 4096 + kk + 4);
            union { s16x8 q; unsigned u[4]; } rr;
            rr.u[0] = pkbf(v0.x, v0.y);
            rr.u[1] = pkbf(v0.z, v0.w);
            rr.u[2] = pkbf(v1.x, v1.y);
            rr.u[3] = pkbf(v1.z, v1.w);
            a[mt] = rr.q;
        }
#pragma unroll
        for (int nt = 0; nt < 4; nt++)
            bb[nt] = *(const s16x8*)(Bp + (size_t)nt * 16 * 4096 + kk);
#pragma unroll
        for (int mt = 0; mt < 2; mt++)
#pragma unroll
            for (int nt = 0; nt < 4; nt++)
                acc[mt][nt] = mfma16(a[mt], bb[nt], acc[mt][nt]);
    }

    // cross-wave K-reduce: wave w -> slice (wj*4+wk) == w
#pragma unroll
    for (int mt = 0; mt < 2; mt++)
#pragma unroll
        for (int nt = 0; nt < 4; nt++)
#pragma unroll
            for (int r = 0; r < 4; r++)
                Ls[w][mt * 16 + quad * 4 + r][nt * 16 + l15] = acc[mt][nt][r];
    __syncthreads();

    int jl = tid >> 3, e0 = (tid & 7) * 8;     // 64 j x (8 e per thread)
    int wjr = jl >> 5, j32 = jl & 31;
    f32x4 s0 = {}, s1 = {};
#pragma unroll
    for (int sk = 0; sk < 4; sk++) {
        const float* Lp = &Ls[wjr * 4 + sk][j32][e0];
        s0 += *(const f32x4*)Lp;
        s1 += *(const f32x4*)(Lp + 4);
    }
    int jg = jb * 64 + jl;
    size_t base = (size_t)ks * 524288
        + ((size_t)(p * 16 + h) * 256 + jg) * 64 + e0;
    *(f32x4*)(accs + base)     = s0;
    *(f32x4*)(accs + base + 4) = s1;
}

// ---- K3: reduce 2 slices + bias + pack ----------------------------------

__global__ __launch_bounds__(256) void packkv_kernel(
        const float* __restrict__ accs, const float* __restrict__ Eb,
        const float* __restrict__ Fb, u16* __restrict__ kp, u16* __restrict__ vpT) {
    int idx = blockIdx.x * 256 + threadIdx.x;
    float v = accs[idx] + accs[idx + 524288];
    int p = idx >> 18, h = (idx >> 14) & 15, j = (idx >> 6) & 255, e = idx & 63;
    if (p == 0) {
        v += Eb[h * 256 + j];
        kp[((size_t)(h * 256 + j)) * 64 + e] = bf(v * 0.125f);  // fold 1/sqrt(64)
    } else {
        v += Fb[h * 256 + j];
        vpT[((size_t)(h * 64 + e)) * 256 + j] = bf(v);
    }
}

// ---- K4: attention: score -> softmax -> PV ------------------------------
// ps col XOR-swizzled by (row&7)<<3: the PV a-frag read (rows at 512B
// stride) was a 16-way bank conflict; swizzle makes it 2-way (free).

__global__ __launch_bounds__(256) void attn_kernel(
        const u16* __restrict__ q, const u16* __restrict__ kp,
        const u16* __restrict__ vpT, u16* __restrict__ zs) {
    __shared__ u16 ps[4][16][256];
    int bm   = blockIdx.x & 63, h = blockIdx.x >> 6;
    int lane = threadIdx.x & 63, w = threadIdx.x >> 6;
    int l15  = lane & 15, quad = lane >> 4;
    int nbase = bm * 64 + w * 16;

    f32x4 s[16] = {};
    const u16* qp  = q  + ((size_t)h * 4096 + nbase + l15) * 64 + quad * 8;
    const u16* kpp = kp + ((size_t)h * 256 + l15) * 64 + quad * 8;
#pragma unroll
    for (int e0 = 0; e0 < 64; e0 += 32) {
        s16x8 a = *(const s16x8*)(qp + e0);
#pragma unroll
        for (int jt = 0; jt < 16; jt++) {
            s16x8 b = *(const s16x8*)(kpp + jt * 16 * 64 + e0);
            s[jt] = mfma16(a, b, s[jt]);
        }
    }

    float lsum[4];
#pragma unroll
    for (int r = 0; r < 4; r++) {
        float m = s[0][r];
#pragma unroll
        for (int jt = 1; jt < 16; jt++) m = fmaxf(m, s[jt][r]);
        m = fmaxf(m, __shfl_xor(m, 1));
        m = fmaxf(m, __shfl_xor(m, 2));
        m = fmaxf(m, __shfl_xor(m, 4));
        m = fmaxf(m, __shfl_xor(m, 8));
        float l = 0.f;
#pragma unroll
        for (int jt = 0; jt < 16; jt++) {
            float pv = __expf(s[jt][r] - m);
            s[jt][r] = pv;
            l += pv;
        }
        l += __shfl_xor(l, 1);
        l += __shfl_xor(l, 2);
        l += __shfl_xor(l, 4);
        l += __shfl_xor(l, 8);
        lsum[r] = l;
    }

#pragma unroll
    for (int jt = 0; jt < 16; jt++)
#pragma unroll
        for (int r = 0; r < 4; r++) {
            int row = quad * 4 + r;
            ps[w][row][(jt * 16 + l15) ^ ((row & 7) << 3)] = bf(s[jt][r]);
        }
    __syncthreads();

    f32x4 z[4] = {};
    const u16* vp = vpT + ((size_t)h * 64 + l15) * 256 + quad * 8;
#pragma unroll
    for (int kj = 0; kj < 8; kj++) {
        s16x8 a = *(const s16x8*)&ps[w][l15][(kj * 32 + quad * 8) ^ ((l15 & 7) << 3)];
#pragma unroll
        for (int et = 0; et < 4; et++) {
            s16x8 b = *(const s16x8*)(vp + et * 16 * 256 + kj * 32);
            z[et] = mfma16(a, b, z[et]);
        }
    }
#pragma unroll
    for (int et = 0; et < 4; et++) {
        int e = et * 16 + l15;
        u16* o = zs + ((size_t)(nbase + quad * 4)) * 1024 + h * 64 + e;
#pragma unroll
        for (int r = 0; r < 4; r++) o[(size_t)r * 1024] = bf(z[et][r] / lsum[r]);
    }
}

// ---- K5: out = zs @ Wo^T, split-K=4, disjoint slices (no atomics) -------

__global__ __launch_bounds__(256) void out_kernel(
        const u16* __restrict__ zs, const u16* __restrict__ wob,
        float* __restrict__ oslice) {
    int ks   = blockIdx.x & 3;
    int bm   = blockIdx.x >> 2;
    int lane = threadIdx.x & 63, w = threadIdx.x >> 6;
    int l15  = lane & 15, quad = lane >> 4;
    int row0 = bm * 128 + w * 32;

    const u16* A = zs  + (size_t)(row0 + l15) * 1024 + ks * 256 + quad * 8;
    const u16* B = wob + (size_t)l15 * 1024 + ks * 256 + quad * 8;

    f32x4 acc[2][4] = {};
    for (int k = 0; k < 256; k += 32) {
        s16x8 a0 = *(const s16x8*)(A + k);
        s16x8 a1 = *(const s16x8*)(A + 16 * 1024 + k);
#pragma unroll
        for (int nt = 0; nt < 4; nt++) {
            s16x8 bv = *(const s16x8*)(B + (size_t)nt * 16 * 1024 + k);
            acc[0][nt] = mfma16(a0, bv, acc[0][nt]);
            acc[1][nt] = mfma16(a1, bv, acc[1][nt]);
        }
    }
    float* os = oslice + (size_t)ks * 262144;
#pragma unroll
    for (int mt = 0; mt < 2; mt++)
#pragma unroll
        for (int nt = 0; nt < 4; nt++) {
            int e = nt * 16 + l15;
            int n0 = row0 + mt * 16 + quad * 4;
            float* o = os + (size_t)n0 * 64 + e;
#pragma unroll
            for (int r = 0; r < 4; r++) o[(size_t)r * 64] = acc[mt][nt][r];
        }
}

__global__ __launch_bounds__(256) void outred_kernel(
        const float* __restrict__ oslice, float* __restrict__ out) {
    int i = blockIdx.x * 256 + threadIdx.x;   // 262144 total
    out[i] = oslice[i] + oslice[i + 262144] + oslice[i + 524288] + oslice[i + 786432];
}

// ---- launch --------------------------------------------------------------

extern "C" void kernel_launch(void* const* d_in, const int* in_sizes, int n_in,
                              void* d_out, int out_size, void* d_ws, size_t ws_size,
                              hipStream_t stream) {
    const float* x  = (const float*)d_in[0];
    const float* Wq = (const float*)d_in[1];
    const float* bq = (const float*)d_in[2];
    const float* Wk = (const float*)d_in[3];
    const float* bk = (const float*)d_in[4];
    const float* Wv = (const float*)d_in[5];
    const float* bv = (const float*)d_in[6];
    const float* Ew = (const float*)d_in[7];
    const float* Eb = (const float*)d_in[8];
    const float* Fw = (const float*)d_in[9];
    const float* Fb = (const float*)d_in[10];
    const float* Wo = (const float*)d_in[11];

    char* ws = (char*)d_ws;
    u16*   qb   = (u16*)(ws + 0);          // H*N*E bf16            8 MB
    u16*   kT   = (u16*)(ws + 8388608);    // H*E*N bf16            8 MB
    u16*   vT   = (u16*)(ws + 16777216);   // H*E*N bf16            8 MB
    u16*   zsb  = (u16*)(ws + 25165824);   // N*(H*E) bf16          8 MB
    float* accs = (float*)(ws + 33554432); // 2 slices x 2 MB fp32 (reused as oslice)
    u16*   kp   = (u16*)(ws + 67108864);   // H*256*64 bf16       0.5 MB
    u16*   vpT  = (u16*)(ws + 67633152);   // H*64*256 bf16       0.5 MB
    u16*   xb   = (u16*)(ws + 68157440);   // N*D bf16              8 MB
    u16*   wb   = (u16*)(ws + 76546048);   // 3*H*E*D bf16          6 MB
    u16*   wob  = (u16*)(ws + 82837504);   // E*(H*E) bf16       128 KB

    cvt_all_kernel<<<7232, 256, 0, stream>>>(x, Wq, Wk, Wv, Wo, xb, wb, wob);
    qkv_kernel<<<768, 256, 0, stream>>>(xb, wb, bq, bk, bv, qb, kT, vT);
    kpvp_kernel<<<256, 512, 0, stream>>>(Ew, Fw, kT, vT, accs);
    packkv_kernel<<<2048, 256, 0, stream>>>(accs, Eb, Fb, kp, vpT);
    attn_kernel<<<1024, 256, 0, stream>>>(qb, kp, vpT, zsb);
    out_kernel<<<128, 256, 0, stream>>>(zsb, wob, (float*)accs);   // accs free -> oslice
    outred_kernel<<<1024, 256, 0, stream>>>((const float*)accs, (float*)d_out);
}

// Round 7
// 264.224 us; speedup vs baseline: 1.1981x; 1.1101x over previous
//
#include <hip/hip_runtime.h>
#include <hip/hip_bf16.h>

typedef __attribute__((ext_vector_type(4))) float f32x4;
typedef __attribute__((ext_vector_type(8))) short s16x8;
typedef __attribute__((ext_vector_type(4))) short s16x4;
typedef unsigned short u16;

// ---- helpers -------------------------------------------------------------

__device__ __forceinline__ f32x4 mfma16(s16x8 a, s16x8 b, f32x4 c) {
    return __builtin_amdgcn_mfma_f32_16x16x32_bf16(a, b, c, 0, 0, 0);
}

// RNE fp32 -> bf16 (bit trick)
__device__ __forceinline__ u16 bf(float f) {
    union { float f; unsigned u; } x; x.f = f;
    return (u16)((x.u + 0x7fffu + ((x.u >> 16) & 1u)) >> 16);
}
__device__ __forceinline__ unsigned pkbf(float a, float b) {
    union { float f; unsigned u; } x, y; x.f = a; y.f = b;
    unsigned ra = x.u + 0x7fffu + ((x.u >> 16) & 1u);
    unsigned rb = y.u + 0x7fffu + ((y.u >> 16) & 1u);
    return (ra >> 16) | (rb & 0xffff0000u);
}

// async global->LDS, 16B per lane (wave-uniform LDS base + lane*16)
__device__ __forceinline__ void gl_lds16(const void* g, void* l) {
    __builtin_amdgcn_global_load_lds(
        (const __attribute__((address_space(1))) unsigned*)g,
        (__attribute__((address_space(3))) unsigned*)l, 16, 0, 0);
}

// ---- K0: merged fp32 -> bf16 convert (x, Wq, Wk, Wv, Wo in one launch) ---

__global__ __launch_bounds__(256) void cvt_all_kernel(
        const float* __restrict__ x,  const float* __restrict__ Wq,
        const float* __restrict__ Wk, const float* __restrict__ Wv,
        const float* __restrict__ Wo,
        u16* __restrict__ xb, u16* __restrict__ wb, u16* __restrict__ wob) {
    int i = blockIdx.x * 256 + threadIdx.x;
    const float* src; u16* dst; int off;
    if (i < 1048576)      { src = x;  dst = xb;            off = i; }
    else if (i < 1310720) { src = Wq; dst = wb;            off = i - 1048576; }
    else if (i < 1572864) { src = Wk; dst = wb + 1048576;  off = i - 1310720; }
    else if (i < 1835008) { src = Wv; dst = wb + 2097152;  off = i - 1572864; }
    else if (i < 1851392) { src = Wo; dst = wob;           off = i - 1835008; }
    else return;
    f32x4 v = ((const f32x4*)src)[off];
    union { s16x4 v; unsigned u[2]; } r;
    r.u[0] = pkbf(v.x, v.y);
    r.u[1] = pkbf(v.z, v.w);
    ((s16x4*)dst)[off] = r.v;
}

// ---- K1: QKV projections, m97-style LDS-staged 128x128 GEMM -------------

__global__ __launch_bounds__(256, 3) void qkv_kernel(
        const u16* __restrict__ xb, const u16* __restrict__ wb,
        const float* __restrict__ bq, const float* __restrict__ bk,
        const float* __restrict__ bv,
        u16* __restrict__ qo, u16* __restrict__ kTo, u16* __restrict__ vTo) {
    __shared__ u16 As[128 * 32];
    __shared__ u16 Bs[128 * 32];
    int bx   = blockIdx.x % 24;
    int by   = blockIdx.x / 24;
    int tid  = threadIdx.x;
    int lane = tid & 63, w = tid >> 6;
    int l15  = lane & 15, quad = lane >> 4;
    int wr   = w >> 1, wc = w & 1;

    const u16* Ag = xb + (size_t)(by * 128 + (tid >> 2)) * 1024 + (tid & 3) * 8;
    const u16* Bg = wb + (size_t)(bx * 128 + (tid >> 2)) * 1024 + (tid & 3) * 8;
    u16* Al = As + tid * 8;
    u16* Bl = Bs + tid * 8;

    const u16* abase = As + (wr * 64 + l15) * 32 + quad * 8;
    const u16* bbase = Bs + (wc * 64 + l15) * 32 + quad * 8;

    f32x4 acc[4][4] = {};
    for (int k0 = 0; k0 < 1024; k0 += 32) {
        gl_lds16(Ag + k0, Al);
        gl_lds16(Ag + 64 * 1024 + k0, Al + 64 * 32);
        gl_lds16(Bg + k0, Bl);
        gl_lds16(Bg + 64 * 1024 + k0, Bl + 64 * 32);
        __syncthreads();
        s16x8 a[4], b[4];
#pragma unroll
        for (int mi = 0; mi < 4; mi++) a[mi] = *(const s16x8*)(abase + mi * 16 * 32);
#pragma unroll
        for (int nj = 0; nj < 4; nj++) b[nj] = *(const s16x8*)(bbase + nj * 16 * 32);
#pragma unroll
        for (int mi = 0; mi < 4; mi++)
#pragma unroll
            for (int nj = 0; nj < 4; nj++) acc[mi][nj] = mfma16(a[mi], b[nj], acc[mi][nj]);
        __syncthreads();
    }

    int fblk = (bx * 128 + wc * 64) >> 6;
    int mat  = fblk >> 4, h = fblk & 15;
    const float* bias = (mat == 0) ? bq : (mat == 1 ? bk : bv);
#pragma unroll
    for (int nj = 0; nj < 4; nj++) {
        int e = nj * 16 + l15;
        float bb = bias[h * 64 + e];
#pragma unroll
        for (int mi = 0; mi < 4; mi++) {
            int n0 = by * 128 + wr * 64 + mi * 16 + quad * 4;
            f32x4 c = acc[mi][nj];
            if (mat == 0) {
                u16* p = qo + ((size_t)h * 4096 + n0) * 64 + e;
#pragma unroll
                for (int r = 0; r < 4; r++) p[(size_t)r * 64] = bf(c[r] + bb);
            } else {
                u16* p = (mat == 1 ? kTo : vTo) + ((size_t)h * 64 + e) * 4096 + n0;
                union { s16x4 v; u16 s[4]; } pk;
#pragma unroll
                for (int r = 0; r < 4; r++) pk.s[r] = bf(c[r] + bb);
                *(s16x4*)p = pk.v;
            }
        }
    }
}

// ---- K2: kp/vp — wave-contiguous staged GEMM, order-robust sync ---------
// 256 blocks (p x h x jb x ks2), 512 thr / 8 waves. Block: 64j x 64e,
// K-half 2048 in 8 stages of 256. Every A global load is ONE ROW x 1 KB
// fully contiguous per instruction; B staged via gl_lds16 with
// pre-swizzled contiguous source. NO counted vmcnt (round-6's race):
// both __syncthreads fully drain, so correctness is independent of the
// compiler's load issue order. A(s+1) prefetch is issued AFTER the
// data-ready barrier and stays in flight across the whole compute phase
// (~1500 cy), draining at the next top-barrier -> latency hidden.
// 16B-chunk XOR swizzle (low3 ^ row&7) on write+read: conflict-free
// ds_read_b128. Wave tile 32j x 16e.

__global__ __launch_bounds__(512, 2) void kpvp_kernel(
        const float* __restrict__ Ew, const float* __restrict__ Fw,
        const u16* __restrict__ kT, const u16* __restrict__ vT,
        float* __restrict__ accs) {
    __shared__ u16 Als[64 * 256];   // 32 KB [j][k], swizzled
    __shared__ u16 Bls[64 * 256];   // 32 KB [e][k], swizzled
    int b   = blockIdx.x;
    int ks  = b & 1, jb = (b >> 1) & 3, h = (b >> 3) & 15, p = b >> 7;
    int tid = threadIdx.x;
    int w = tid >> 6, lane = tid & 63;
    int l15 = lane & 15, quad = lane >> 4;
    int wm = w >> 2, we = w & 3;    // wave tile: 32 j x 16 e

    const float* Abase = (p ? Fw : Ew)
        + (size_t)(h * 256 + jb * 64) * 4096 + ks * 2048;
    const char* Bbase = (const char*)(p ? vT : kT)
        + (size_t)h * 64 * 8192 + ks * 4096;

    f32x4 areg[8];
#pragma unroll
    for (int pr = 0; pr < 8; pr++)
        areg[pr] = *(const f32x4*)(Abase + (size_t)(pr * 8 + w) * 4096 + lane * 4);

    f32x4 acc[2] = {};

#pragma unroll
    for (int s = 0; s < 8; s++) {
        __syncthreads();       // buffer free; drains A(s) regs (full fence)
        // stage B(s) first: its latency hides under A convert+ds_write
#pragma unroll
        for (int i = 0; i < 4; i++) {
            int row = (w * 4 + i) * 2 + (lane >> 5);
            int c   = lane & 31;
            int cg  = (c & 24) | ((c & 7) ^ (row & 7));
            gl_lds16(Bbase + (size_t)row * 8192 + s * 512 + cg * 16,
                     (char*)Bls + (w * 4 + i) * 1024);
        }
        // convert + ds_write A(s): row = pr*8+w, row&7 == w&7
#pragma unroll
        for (int pr = 0; pr < 8; pr++) {
            int row = pr * 8 + w;
            union { s16x4 q; unsigned u[2]; } rr;
            rr.u[0] = pkbf(areg[pr].x, areg[pr].y);
            rr.u[1] = pkbf(areg[pr].z, areg[pr].w);
            int c  = lane >> 1;
            int cw = (c & 24) | ((c & 7) ^ (w & 7));
            *(s16x4*)((char*)Als + row * 512 + cw * 16 + (lane & 1) * 8) = rr.q;
        }
        __syncthreads();       // data ready: compiler drains vmcnt0+lgkm0
        // prefetch A(s+1): 1 KB contiguous per inst, flies across compute
        if (s < 7) {
#pragma unroll
            for (int pr = 0; pr < 8; pr++)
                areg[pr] = *(const f32x4*)(Abase + (size_t)(pr * 8 + w) * 4096
                                           + (s + 1) * 256 + lane * 4);
        }
        // compute(s)
#pragma unroll
        for (int t = 0; t < 8; t++) {
            int c  = 4 * t + quad;
            int ca = (c & 24) | ((c & 7) ^ (l15 & 7));
            s16x8 bv = *(const s16x8*)((char*)Bls + (we * 16 + l15) * 512 + ca * 16);
            s16x8 a0 = *(const s16x8*)((char*)Als + (wm * 32 + l15) * 512 + ca * 16);
            s16x8 a1 = *(const s16x8*)((char*)Als + (wm * 32 + 16 + l15) * 512 + ca * 16);
            acc[0] = mfma16(a0, bv, acc[0]);
            acc[1] = mfma16(a1, bv, acc[1]);
        }
    }

    size_t obase = (size_t)ks * 524288 + ((size_t)(p * 16 + h) * 256 + jb * 64) * 64;
#pragma unroll
    for (int mt = 0; mt < 2; mt++)
#pragma unroll
        for (int r = 0; r < 4; r++) {
            int jrow = wm * 32 + mt * 16 + quad * 4 + r;
            accs[obase + (size_t)jrow * 64 + we * 16 + l15] = acc[mt][r];
        }
}

// ---- K3: reduce 2 slices + bias + pack ----------------------------------

__global__ __launch_bounds__(256) void packkv_kernel(
        const float* __restrict__ accs, const float* __restrict__ Eb,
        const float* __restrict__ Fb, u16* __restrict__ kp, u16* __restrict__ vpT) {
    int idx = blockIdx.x * 256 + threadIdx.x;
    float v = accs[idx] + accs[idx + 524288];
    int p = idx >> 18, h = (idx >> 14) & 15, j = (idx >> 6) & 255, e = idx & 63;
    if (p == 0) {
        v += Eb[h * 256 + j];
        kp[((size_t)(h * 256 + j)) * 64 + e] = bf(v * 0.125f);  // fold 1/sqrt(64)
    } else {
        v += Fb[h * 256 + j];
        vpT[((size_t)(h * 64 + e)) * 256 + j] = bf(v);
    }
}

// ---- K4: attention: LDS-staged kp/vp (time-shared buffer) ---------------
// kp (32 KB) staged coalesced+swizzled; QK^T b-frags from LDS; after a
// barrier the SAME buffer is restaged with vp for PV. All fragment reads
// conflict-free via low-3-bit chunk XOR. ps per-wave private (swizzled).
// All sync via __syncthreads (full drain) -> no ordering assumptions.

__global__ __launch_bounds__(256, 2) void attn_kernel(
        const u16* __restrict__ q, const u16* __restrict__ kp,
        const u16* __restrict__ vpT, u16* __restrict__ zs) {
    __shared__ u16 kv[16384];          // 32 KB, kp then vp
    __shared__ u16 ps[4][16][256];     // 32 KB
    int bm   = blockIdx.x & 63, h = blockIdx.x >> 6;
    int tid  = threadIdx.x;
    int lane = tid & 63, w = tid >> 6;
    int l15  = lane & 15, quad = lane >> 4;
    int nbase = bm * 64 + w * 16;

    // stage kp[h]: 256 rows x 128 B, 8 chunks/row, chunk ^= row&7
    {
        int r8 = lane >> 3;
        int cg = (lane & 7) ^ r8;
        const u16* src = kp + (size_t)h * 16384;
#pragma unroll
        for (int it = 0; it < 8; it++) {
            int row = it * 32 + w * 8 + r8;
            gl_lds16(src + row * 64 + cg * 8, (char*)kv + it * 4096 + w * 1024);
        }
    }
    const u16* qp = q + ((size_t)h * 4096 + nbase + l15) * 64 + quad * 8;
    s16x8 qa0 = *(const s16x8*)(qp);
    s16x8 qa1 = *(const s16x8*)(qp + 32);
    __syncthreads();                   // kp staged (drains vmcnt)

    f32x4 s[16] = {};
#pragma unroll
    for (int jt = 0; jt < 16; jt++) {
        int c0 = quad ^ (l15 & 7);
        int c1 = (quad + 4) ^ (l15 & 7);
        const char* rowp = (const char*)kv + (jt * 16 + l15) * 128;
        s16x8 b0 = *(const s16x8*)(rowp + c0 * 16);
        s16x8 b1 = *(const s16x8*)(rowp + c1 * 16);
        s[jt] = mfma16(qa0, b0, s[jt]);
        s[jt] = mfma16(qa1, b1, s[jt]);
    }

    float lsum[4];
#pragma unroll
    for (int r = 0; r < 4; r++) {
        float m = s[0][r];
#pragma unroll
        for (int jt = 1; jt < 16; jt++) m = fmaxf(m, s[jt][r]);
        m = fmaxf(m, __shfl_xor(m, 1));
        m = fmaxf(m, __shfl_xor(m, 2));
        m = fmaxf(m, __shfl_xor(m, 4));
        m = fmaxf(m, __shfl_xor(m, 8));
        float l = 0.f;
#pragma unroll
        for (int jt = 0; jt < 16; jt++) {
            float pv = __expf(s[jt][r] - m);
            s[jt][r] = pv;
            l += pv;
        }
        l += __shfl_xor(l, 1);
        l += __shfl_xor(l, 2);
        l += __shfl_xor(l, 4);
        l += __shfl_xor(l, 8);
        lsum[r] = l;
    }

    __syncthreads();                   // all waves done reading kp
    // stage vp[h]: 64 rows x 512 B, 32 chunks/row, low3 ^= row&7
    {
        int r2 = lane >> 5;
        int c  = lane & 31;
        const u16* src = vpT + (size_t)h * 16384;
#pragma unroll
        for (int it = 0; it < 8; it++) {
            int row = it * 8 + w * 2 + r2;
            int cg  = (c & 24) | ((c & 7) ^ (row & 7));
            gl_lds16(src + row * 256 + cg * 8, (char*)kv + it * 4096 + w * 1024);
        }
    }
    // write ps (per-wave private, swizzled) — overlaps vp staging latency
#pragma unroll
    for (int jt = 0; jt < 16; jt++)
#pragma unroll
        for (int r = 0; r < 4; r++) {
            int row = quad * 4 + r;
            ps[w][row][(jt * 16 + l15) ^ ((row & 7) << 3)] = bf(s[jt][r]);
        }
    __syncthreads();                   // vp staged (drains vmcnt)

    f32x4 z[4] = {};
#pragma unroll
    for (int kj = 0; kj < 8; kj++) {
        s16x8 a = *(const s16x8*)&ps[w][l15][(kj * 32 + quad * 8) ^ ((l15 & 7) << 3)];
#pragma unroll
        for (int et = 0; et < 4; et++) {
            int c  = kj * 4 + quad;
            int cs = (c & 24) | ((c & 7) ^ (l15 & 7));
            s16x8 bv = *(const s16x8*)((char*)kv + (et * 16 + l15) * 512 + cs * 16);
            z[et] = mfma16(a, bv, z[et]);
        }
    }
#pragma unroll
    for (int et = 0; et < 4; et++) {
        int e = et * 16 + l15;
        u16* o = zs + ((size_t)(nbase + quad * 4)) * 1024 + h * 64 + e;
#pragma unroll
        for (int r = 0; r < 4; r++) o[(size_t)r * 1024] = bf(z[et][r] / lsum[r]);
    }
}

// ---- K5: out = zs @ Wo^T, split-K=4, disjoint slices (no atomics) -------

__global__ __launch_bounds__(256) void out_kernel(
        const u16* __restrict__ zs, const u16* __restrict__ wob,
        float* __restrict__ oslice) {
    int ks   = blockIdx.x & 3;
    int bm   = blockIdx.x >> 2;
    int lane = threadIdx.x & 63, w = threadIdx.x >> 6;
    int l15  = lane & 15, quad = lane >> 4;
    int row0 = bm * 128 + w * 32;

    const u16* A = zs  + (size_t)(row0 + l15) * 1024 + ks * 256 + quad * 8;
    const u16* B = wob + (size_t)l15 * 1024 + ks * 256 + quad * 8;

    f32x4 acc[2][4] = {};
    for (int k = 0; k < 256; k += 32) {
        s16x8 a0 = *(const s16x8*)(A + k);
        s16x8 a1 = *(const s16x8*)(A + 16 * 1024 + k);
#pragma unroll
        for (int nt = 0; nt < 4; nt++) {
            s16x8 bv = *(const s16x8*)(B + (size_t)nt * 16 * 1024 + k);
            acc[0][nt] = mfma16(a0, bv, acc[0][nt]);
            acc[1][nt] = mfma16(a1, bv, acc[1][nt]);
        }
    }
    float* os = oslice + (size_t)ks * 262144;
#pragma unroll
    for (int mt = 0; mt < 2; mt++)
#pragma unroll
        for (int nt = 0; nt < 4; nt++) {
            int e = nt * 16 + l15;
            int n0 = row0 + mt * 16 + quad * 4;
            float* o = os + (size_t)n0 * 64 + e;
#pragma unroll
            for (int r = 0; r < 4; r++) o[(size_t)r * 64] = acc[mt][nt][r];
        }
}

__global__ __launch_bounds__(256) void outred_kernel(
        const float* __restrict__ oslice, float* __restrict__ out) {
    int i = blockIdx.x * 256 + threadIdx.x;   // 262144 total
    out[i] = oslice[i] + oslice[i + 262144] + oslice[i + 524288] + oslice[i + 786432];
}

// ---- launch --------------------------------------------------------------

extern "C" void kernel_launch(void* const* d_in, const int* in_sizes, int n_in,
                              void* d_out, int out_size, void* d_ws, size_t ws_size,
                              hipStream_t stream) {
    const float* x  = (const float*)d_in[0];
    const float* Wq = (const float*)d_in[1];
    const float* bq = (const float*)d_in[2];
    const float* Wk = (const float*)d_in[3];
    const float* bk = (const float*)d_in[4];
    const float* Wv = (const float*)d_in[5];
    const float* bv = (const float*)d_in[6];
    const float* Ew = (const float*)d_in[7];
    const float* Eb = (const float*)d_in[8];
    const float* Fw = (const float*)d_in[9];
    const float* Fb = (const float*)d_in[10];
    const float* Wo = (const float*)d_in[11];

    char* ws = (char*)d_ws;
    u16*   qb   = (u16*)(ws + 0);          // H*N*E bf16            8 MB
    u16*   kT   = (u16*)(ws + 8388608);    // H*E*N bf16            8 MB
    u16*   vT   = (u16*)(ws + 16777216);   // H*E*N bf16            8 MB
    u16*   zsb  = (u16*)(ws + 25165824);   // N*(H*E) bf16          8 MB
    float* accs = (float*)(ws + 33554432); // 2 slices x 2 MB fp32 (reused as oslice)
    u16*   kp   = (u16*)(ws + 67108864);   // H*256*64 bf16       0.5 MB
    u16*   vpT  = (u16*)(ws + 67633152);   // H*64*256 bf16       0.5 MB
    u16*   xb   = (u16*)(ws + 68157440);   // N*D bf16              8 MB
    u16*   wb   = (u16*)(ws + 76546048);   // 3*H*E*D bf16          6 MB
    u16*   wob  = (u16*)(ws + 82837504);   // E*(H*E) bf16       128 KB

    cvt_all_kernel<<<7232, 256, 0, stream>>>(x, Wq, Wk, Wv, Wo, xb, wb, wob);
    qkv_kernel<<<768, 256, 0, stream>>>(xb, wb, bq, bk, bv, qb, kT, vT);
    kpvp_kernel<<<256, 512, 0, stream>>>(Ew, Fw, kT, vT, accs);
    packkv_kernel<<<2048, 256, 0, stream>>>(accs, Eb, Fb, kp, vpT);
    attn_kernel<<<1024, 256, 0, stream>>>(qb, kp, vpT, zsb);
    out_kernel<<<128, 256, 0, stream>>>(zsb, wob, (float*)accs);   // accs free -> oslice
    outred_kernel<<<1024, 256, 0, stream>>>((const float*)accs, (float*)d_out);
}